// Round 22
// baseline (133.355 us; speedup 1.0000x reference)
//
#include <hip/hip_runtime.h>
#include <hip/hip_fp16.h>
#include <math.h>

#define N_NODES 50000
#define F_DIM   128
#define E_EDGES 800000
#define NPB     32      // nodes per gemm block -> 1563 blocks (last block 16 rows)
#define NBLK    1563
#define SUBCAP  32      // per-parity bucket capacity (Poisson(8): P(>32) ~ 1e-13)
#define APAD_H  136     // padded row stride in halves (272 B = 17 x 16B)
#define NMASKW  400000  // 12.8M elements / 32 bits
#define FILL_BLOCKS (E_EDGES / 256)            // 3125
#define PACK_BLOCKS ((N_NODES * F_DIM) / 1024) // 6250
#define WPACK_BLOCKS 64                        // 2*128*64 half2 words / 256

typedef _Float16 f16x8 __attribute__((ext_vector_type(8)));
typedef float    f32x4 __attribute__((ext_vector_type(4)));

// ---------------- JAX threefry (partitionable path, o0^o1) — verified r2 ----------------
__device__ __forceinline__ unsigned rotl32(unsigned x, int d) {
  return (x << d) | (x >> (32 - d));
}

__device__ __forceinline__ void tf2x32(unsigned k0, unsigned k1,
                                       unsigned c0, unsigned c1,
                                       unsigned &o0, unsigned &o1) {
  unsigned ks2 = k0 ^ k1 ^ 0x1BD11BDAu;
  unsigned x0 = c0 + k0, x1 = c1 + k1;
#define TF_R(a) { x0 += x1; x1 = rotl32(x1, a); x1 ^= x0; }
  TF_R(13) TF_R(15) TF_R(26) TF_R(6)   x0 += k1;  x1 += ks2 + 1u;
  TF_R(17) TF_R(29) TF_R(16) TF_R(24)  x0 += ks2; x1 += k0 + 2u;
  TF_R(13) TF_R(15) TF_R(26) TF_R(6)   x0 += k0;  x1 += k1 + 3u;
  TF_R(17) TF_R(29) TF_R(16) TF_R(24)  x0 += k1;  x1 += ks2 + 4u;
  TF_R(13) TF_R(15) TF_R(26) TF_R(6)   x0 += ks2; x1 += k0 + 5u;
#undef TF_R
  o0 = x0; o1 = x1;
}

__device__ __forceinline__ bool keep_elem(unsigned j) {
  unsigned o0, o1;
  tf2x32(0u, 42u, 0u, j, o0, o1);
  unsigned bits = o0 ^ o1;
  float uf = __uint_as_float((bits >> 9) | 0x3f800000u) - 1.0f;
  return uf < 0.7f;
}

// --- prep: bucket fill (2 parity sub-cursors) + mask | fp16 x pack | c-major W pack ---
// cursor[(e&1)*N + d]: halves same-address atomic contention (16 -> 8 avg) and
// doubles cursor-line spread. Parity p owns bucket slots [p*32, p*32+32).
__global__ __launch_bounds__(256) void prep(const float* __restrict__ x,
                                            __half* __restrict__ xh,
                                            const int* __restrict__ src,
                                            const int* __restrict__ dst,
                                            const float* __restrict__ Wself,
                                            const float* __restrict__ Wneigh,
                                            float* __restrict__ Wp,
                                            int* __restrict__ cursor,
                                            unsigned short* __restrict__ bucket,
                                            unsigned* __restrict__ mask) {
  int b = blockIdx.x;
  if (b < FILL_BLOCKS) {
    int e = b * 256 + threadIdx.x;
    int d = dst[e];
    int par = e & 1;
    int pos = atomicAdd(&cursor[par * N_NODES + d], 1);
    if (pos < SUBCAP)
      bucket[(par * SUBCAP + pos) * N_NODES + d] = (unsigned short)src[e];
    if (e < NMASKW) {                       // threefry hides under memory stalls
      unsigned base = (unsigned)e * 32u;
      unsigned w = 0;
#pragma unroll 4
      for (int bb = 0; bb < 32; ++bb) w |= (keep_elem(base + bb) ? 1u : 0u) << bb;
      mask[e] = w;
    }
  } else if (b < FILL_BLOCKS + PACK_BLOCKS) {
    int i = (b - FILL_BLOCKS) * 256 + threadIdx.x;   // one float4 -> 8B half4
    float4 v = ((const float4*)x)[i];
    __half2 h01 = __floats2half2_rn(v.x, v.y);
    __half2 h23 = __floats2half2_rn(v.z, v.w);
    float2 o;
    o.x = __uint_as_float(*(const unsigned*)&h01);
    o.y = __uint_as_float(*(const unsigned*)&h23);
    ((float2*)xh)[i] = o;
  } else {
    // W pack, c-major k-pairs: Wp[h][c][k2] = half2(W[2k2][c], W[2k2+1][c])
    int idx = (b - FILL_BLOCKS - PACK_BLOCKS) * 256 + threadIdx.x;  // [0, 16384)
    int h = idx >> 13, rem = idx & 8191;
    int k2 = rem >> 7, c = rem & 127;
    const float* Ws = h ? Wneigh : Wself;
    __half2 hh = __floats2half2_rn(Ws[(k2 * 2) * 128 + c], Ws[(k2 * 2 + 1) * 128 + c]);
    Wp[h * 8192 + c * 64 + k2] = __builtin_bit_cast(float, hh);
  }
}

// ---- gather: one 64-lane wave per node; two parity runs; 16 loads in flight ----
__global__ __launch_bounds__(256) void gather_kernel(const __half* __restrict__ xh,
                                                     const int* __restrict__ cursor,
                                                     const unsigned short* __restrict__ bucket,
                                                     __half* __restrict__ seg) {
  const int w = threadIdx.x >> 6, li = threadIdx.x & 63;
  const int n = blockIdx.x * 4 + w;          // 12500 * 4 = 50000 exactly
  int d0 = cursor[n];            d0 = d0 < SUBCAP ? d0 : SUBCAP;
  int d1 = cursor[N_NODES + n];  d1 = d1 < SUBCAP ? d1 : SUBCAP;
  const int deg = d0 + d1;
  __half2 sum = __floats2half2_rn(0.f, 0.f);
  const unsigned* xr = (const unsigned*)xh;  // dword = half2; row stride 64
#pragma unroll
  for (int p = 0; p < 2; ++p) {
    const int dp = p ? d1 : d0;
    const int base = p * SUBCAP;
    for (int j0 = 0; j0 < dp; j0 += 16) {
      int idx[16];
#pragma unroll
      for (int k = 0; k < 16; ++k) {
        int j = j0 + k;
        j = j < dp ? j : dp - 1;             // clamped -> always a valid slot
        idx[k] = bucket[(size_t)(base + j) * N_NODES + n];
      }
      unsigned u[16];
#pragma unroll
      for (int k = 0; k < 16; ++k)
        u[k] = xr[(size_t)idx[k] * 64 + li]; // 16 independent coalesced dwords
#pragma unroll
      for (int k = 0; k < 16; ++k)
        if (j0 + k < dp)
          sum = __hadd2(sum, __builtin_bit_cast(__half2, u[k]));
    }
  }
  float iv = 1.0f / (float)(deg > 1 ? deg : 1);
  float2 f = __half22float2(sum);
  __half2 r = __floats2half2_rn(f.x * iv, f.y * iv);
  ((unsigned*)seg)[(size_t)n * 64 + li] = __builtin_bit_cast(unsigned, r);
}

// ---- gemm: MFMA 16x16x32_f16. 512 thr = 8 waves; wave (h, rb, cbg) owns 4 16x16 tiles ----
// A: row=lane&15, k=(lane>>4)*8+j.  B: col=lane&15, k likewise.
// C/D: col=lane&15, row=(lane>>4)*4+reg  [verified m89 + r18 pass].
__global__ __launch_bounds__(512) void gemm_kernel(
    const __half* __restrict__ xh, const __half* __restrict__ seg,
    const float* __restrict__ Wp, const float* __restrict__ bias,
    const unsigned* __restrict__ mask, float* __restrict__ out) {
  __shared__ __align__(16) __half Ah[2][NPB][APAD_H];   // 17.4 KB
  __shared__ float wsum[2][2][2][16];                   // [rb][h][cbg][row16]

  const int t = threadIdx.x;
  const int row0 = blockIdx.x * NPB;

  // ---- stage self + mean rows (1024 x 16B granules, 2/thread, coalesced) ----
#pragma unroll
  for (int k = 0; k < 2; ++k) {
    int q = k * 512 + t;
    int arr = q >> 9, rem = q & 511;
    int row = rem >> 4, f8 = rem & 15;
    int grow = row0 + row;
    if (grow > N_NODES - 1) grow = N_NODES - 1;
    const __half* sp = arr ? seg : xh;
    *(float4*)&Ah[arr][row][f8 * 8] = ((const float4*)sp)[(size_t)grow * 16 + f8];
  }
  __syncthreads();

  const int wid = t >> 6, lane = t & 63;
  const int h = wid >> 2, rb = wid & 1, cbg = (wid >> 1) & 1;
  const int c15 = lane & 15, hi = lane >> 4;

  // ---- A fragments: 4 k-chunks of this wave's 16-row block ----
  f16x8 afrag[4];
#pragma unroll
  for (int kc = 0; kc < 4; ++kc)
    afrag[kc] = *(const f16x8*)&Ah[h][rb * 16 + c15][kc * 32 + hi * 8];

  // ---- MFMA: 4 col-tiles x 4 K-chunks ----
  const float4* Wb4 = (const float4*)Wp + h * 2048;   // [c][16 float4 of k-pairs]
  f32x4 acc[4];
#pragma unroll
  for (int ct = 0; ct < 4; ++ct) acc[ct] = (f32x4){0.f, 0.f, 0.f, 0.f};

#pragma unroll
  for (int ct = 0; ct < 4; ++ct) {
    int col_h = cbg * 64 + ct * 16 + c15;
#pragma unroll
    for (int kc = 0; kc < 4; ++kc) {
      float4 br = Wb4[col_h * 16 + kc * 4 + hi];
      acc[ct] = __builtin_amdgcn_mfma_f32_16x16x32_f16(
          afrag[kc], __builtin_bit_cast(f16x8, br), acc[ct], 0, 0, 0);
    }
  }

  // ---- epilogue: +bias, ELU, dropout (bitmask), partial sum-of-squares ----
  float ssr[4] = {0.f, 0.f, 0.f, 0.f};
#pragma unroll
  for (int ct = 0; ct < 4; ++ct) {
    int col_h = cbg * 64 + ct * 16 + c15;
    float b = bias[h * 128 + col_h];
#pragma unroll
    for (int reg = 0; reg < 4; ++reg) {
      unsigned n = row0 + rb * 16 + hi * 4 + reg;
      float val = acc[ct][reg] + b;
      val = (val > 0.0f) ? val : expm1f(val);
      unsigned mw = (n < N_NODES)
                        ? mask[n * 8u + (unsigned)h * 4u + (unsigned)(cbg * 2 + (ct >> 1))]
                        : 0u;
      val = ((mw >> ((ct & 1) * 16 + c15)) & 1u) ? val * (1.0f / 0.7f) : 0.0f;
      acc[ct][reg] = val;
      ssr[reg] = fmaf(val, val, ssr[reg]);
    }
  }
  // reduce over the 16 col-lanes (width 16 stays within the hi group)
#pragma unroll
  for (int d = 1; d < 16; d <<= 1)
#pragma unroll
    for (int reg = 0; reg < 4; ++reg) ssr[reg] += __shfl_xor(ssr[reg], d, 16);
  if (c15 == 0) {
#pragma unroll
    for (int reg = 0; reg < 4; ++reg) wsum[rb][h][cbg][hi * 4 + reg] = ssr[reg];
  }
  __syncthreads();

  // ---- l2norm + store ----
#pragma unroll
  for (int reg = 0; reg < 4; ++reg) {
    int r16 = hi * 4 + reg;
    float tot = wsum[rb][0][0][r16] + wsum[rb][0][1][r16] +
                wsum[rb][1][0][r16] + wsum[rb][1][1][r16];
    float sc = rsqrtf(fmaxf(tot, 1e-12f));
    size_t n = (size_t)(row0 + rb * 16 + r16);
    if (n < N_NODES) {
#pragma unroll
      for (int ct = 0; ct < 4; ++ct)
        out[n * 256 + h * 128 + cbg * 64 + ct * 16 + c15] = acc[ct][reg] * sc;
    }
  }
}

extern "C" void kernel_launch(void* const* d_in, const int* in_sizes, int n_in,
                              void* d_out, int out_size, void* d_ws, size_t ws_size,
                              hipStream_t stream) {
  const float* x      = (const float*)d_in[0];
  const float* Wself  = (const float*)d_in[1];
  const float* Wneigh = (const float*)d_in[2];
  const float* bias   = (const float*)d_in[3];
  const int*   src    = (const int*)d_in[4];   // jnp.int64 degrades to int32 (x64 off)
  const int*   dst    = (const int*)d_in[5];
  float* out = (float*)d_out;

  char* p = (char*)d_ws;
  int*            cursor = (int*)p;                       // 400,000 B (pad 400,896)
  unsigned short* bucket = (unsigned short*)(p + 400896); // 6,400,000 B (slot-major)
  __half*         seg    = (__half*)(p + 6800896);        // 12,800,000 B
  __half*         xh     = (__half*)(p + 19600896);       // 12,800,000 B
  unsigned*       mask   = (unsigned*)(p + 32400896);     // 1,600,000 B
  float*          Wp     = (float*)(p + 34000896);        // 65,536 B (end ~34.1 MB)

  hipMemsetAsync(cursor, 0, 400000, stream);
  prep<<<FILL_BLOCKS + PACK_BLOCKS + WPACK_BLOCKS, 256, 0, stream>>>(
      x, xh, src, dst, Wself, Wneigh, Wp, cursor, bucket, mask);
  gather_kernel<<<N_NODES / 4, 256, 0, stream>>>(xh, cursor, bucket, seg);
  gemm_kernel  <<<NBLK, 512, 0, stream>>>(xh, seg, Wp, bias, mask, out);
}

// Round 23
// 127.672 us; speedup vs baseline: 1.0445x; 1.0445x over previous
//
#include <hip/hip_runtime.h>
#include <hip/hip_fp16.h>
#include <math.h>

#define N_NODES 50000
#define F_DIM   128
#define E_EDGES 800000
#define NPB     32      // nodes per gemm block -> 1563 blocks (last block 16 rows)
#define NBLK    1563
#define SUBCAP  32      // per-parity bucket capacity (Poisson(8): P(>32) ~ 1e-13)
#define APAD_H  136     // padded row stride in halves (272 B = 17 x 16B)
#define NMASKW  400000  // 12.8M elements / 32 bits
#define FILL_BLOCKS 782 // 4 edges/thread: 782*1024 = 800,768 >= E_EDGES
#define PACK_BLOCKS ((N_NODES * F_DIM) / 1024) // 6250
#define WPACK_BLOCKS 64                        // 2*128*64 half2 words / 256

typedef _Float16 f16x8 __attribute__((ext_vector_type(8)));
typedef float    f32x4 __attribute__((ext_vector_type(4)));

// ---------------- JAX threefry (partitionable path, o0^o1) — verified r2 ----------------
__device__ __forceinline__ unsigned rotl32(unsigned x, int d) {
  return (x << d) | (x >> (32 - d));
}

__device__ __forceinline__ void tf2x32(unsigned k0, unsigned k1,
                                       unsigned c0, unsigned c1,
                                       unsigned &o0, unsigned &o1) {
  unsigned ks2 = k0 ^ k1 ^ 0x1BD11BDAu;
  unsigned x0 = c0 + k0, x1 = c1 + k1;
#define TF_R(a) { x0 += x1; x1 = rotl32(x1, a); x1 ^= x0; }
  TF_R(13) TF_R(15) TF_R(26) TF_R(6)   x0 += k1;  x1 += ks2 + 1u;
  TF_R(17) TF_R(29) TF_R(16) TF_R(24)  x0 += ks2; x1 += k0 + 2u;
  TF_R(13) TF_R(15) TF_R(26) TF_R(6)   x0 += k0;  x1 += k1 + 3u;
  TF_R(17) TF_R(29) TF_R(16) TF_R(24)  x0 += k1;  x1 += ks2 + 4u;
  TF_R(13) TF_R(15) TF_R(26) TF_R(6)   x0 += ks2; x1 += k0 + 5u;
#undef TF_R
  o0 = x0; o1 = x1;
}

__device__ __forceinline__ bool keep_elem(unsigned j) {
  unsigned o0, o1;
  tf2x32(0u, 42u, 0u, j, o0, o1);
  unsigned bits = o0 ^ o1;
  float uf = __uint_as_float((bits >> 9) | 0x3f800000u) - 1.0f;
  return uf < 0.7f;
}

// --- prep: fill (4 atomic chains/thread, pure) | fp16 x pack + mask | c-major W pack ---
__global__ __launch_bounds__(256) void prep(const float* __restrict__ x,
                                            __half* __restrict__ xh,
                                            const int* __restrict__ src,
                                            const int* __restrict__ dst,
                                            const float* __restrict__ Wself,
                                            const float* __restrict__ Wneigh,
                                            float* __restrict__ Wp,
                                            int* __restrict__ cursor,
                                            unsigned short* __restrict__ bucket,
                                            unsigned* __restrict__ mask) {
  int b = blockIdx.x;
  if (b < FILL_BLOCKS) {
    // 4 independent {load dst -> atomic -> store} chains per thread
#pragma unroll
    for (int k = 0; k < 4; ++k) {
      int e = b * 1024 + k * 256 + threadIdx.x;
      if (e < E_EDGES) {
        int d = dst[e];
        int par = e & 1;
        int pos = atomicAdd(&cursor[par * N_NODES + d], 1);
        if (pos < SUBCAP)
          bucket[(par * SUBCAP + pos) * N_NODES + d] = (unsigned short)src[e];
      }
    }
  } else if (b < FILL_BLOCKS + PACK_BLOCKS) {
    int i = (b - FILL_BLOCKS) * 256 + threadIdx.x;   // one float4 -> 8B half4
    float4 v = ((const float4*)x)[i];
    __half2 h01 = __floats2half2_rn(v.x, v.y);
    __half2 h23 = __floats2half2_rn(v.z, v.w);
    float2 o;
    o.x = __uint_as_float(*(const unsigned*)&h01);
    o.y = __uint_as_float(*(const unsigned*)&h23);
    ((float2*)xh)[i] = o;
    if (i < NMASKW) {                       // threefry hides under pack's idle VALU
      unsigned base = (unsigned)i * 32u;
      unsigned w = 0;
#pragma unroll 4
      for (int bb = 0; bb < 32; ++bb) w |= (keep_elem(base + bb) ? 1u : 0u) << bb;
      mask[i] = w;
    }
  } else {
    // W pack, c-major k-pairs: Wp[h][c][k2] = half2(W[2k2][c], W[2k2+1][c])
    int idx = (b - FILL_BLOCKS - PACK_BLOCKS) * 256 + threadIdx.x;  // [0, 16384)
    int h = idx >> 13, rem = idx & 8191;
    int k2 = rem >> 7, c = rem & 127;
    const float* Ws = h ? Wneigh : Wself;
    __half2 hh = __floats2half2_rn(Ws[(k2 * 2) * 128 + c], Ws[(k2 * 2 + 1) * 128 + c]);
    Wp[h * 8192 + c * 64 + k2] = __builtin_bit_cast(float, hh);
  }
}

// ---- gather: one 64-lane wave per node; two parity runs; 16 loads in flight ----
__global__ __launch_bounds__(256) void gather_kernel(const __half* __restrict__ xh,
                                                     const int* __restrict__ cursor,
                                                     const unsigned short* __restrict__ bucket,
                                                     __half* __restrict__ seg) {
  const int w = threadIdx.x >> 6, li = threadIdx.x & 63;
  const int n = blockIdx.x * 4 + w;          // 12500 * 4 = 50000 exactly
  int d0 = cursor[n];            d0 = d0 < SUBCAP ? d0 : SUBCAP;
  int d1 = cursor[N_NODES + n];  d1 = d1 < SUBCAP ? d1 : SUBCAP;
  const int deg = d0 + d1;
  __half2 sum = __floats2half2_rn(0.f, 0.f);
  const unsigned* xr = (const unsigned*)xh;  // dword = half2; row stride 64
#pragma unroll
  for (int p = 0; p < 2; ++p) {
    const int dp = p ? d1 : d0;
    const int base = p * SUBCAP;
    for (int j0 = 0; j0 < dp; j0 += 16) {
      int idx[16];
#pragma unroll
      for (int k = 0; k < 16; ++k) {
        int j = j0 + k;
        j = j < dp ? j : dp - 1;             // clamped -> always a valid slot
        idx[k] = bucket[(size_t)(base + j) * N_NODES + n];
      }
      unsigned u[16];
#pragma unroll
      for (int k = 0; k < 16; ++k)
        u[k] = xr[(size_t)idx[k] * 64 + li]; // 16 independent coalesced dwords
#pragma unroll
      for (int k = 0; k < 16; ++k)
        if (j0 + k < dp)
          sum = __hadd2(sum, __builtin_bit_cast(__half2, u[k]));
    }
  }
  float iv = 1.0f / (float)(deg > 1 ? deg : 1);
  float2 f = __half22float2(sum);
  __half2 r = __floats2half2_rn(f.x * iv, f.y * iv);
  ((unsigned*)seg)[(size_t)n * 64 + li] = __builtin_bit_cast(unsigned, r);
}

// ---- gemm: MFMA 16x16x32_f16. 512 thr = 8 waves; wave (h, rb, cbg) owns 4 16x16 tiles ----
// A: row=lane&15, k=(lane>>4)*8+j.  B: col=lane&15, k likewise.
// C/D: col=lane&15, row=(lane>>4)*4+reg  [verified m89 + r18 pass].
__global__ __launch_bounds__(512) void gemm_kernel(
    const __half* __restrict__ xh, const __half* __restrict__ seg,
    const float* __restrict__ Wp, const float* __restrict__ bias,
    const unsigned* __restrict__ mask, float* __restrict__ out) {
  __shared__ __align__(16) __half Ah[2][NPB][APAD_H];   // 17.4 KB
  __shared__ float wsum[2][2][2][16];                   // [rb][h][cbg][row16]

  const int t = threadIdx.x;
  const int row0 = blockIdx.x * NPB;

  // ---- stage self + mean rows (1024 x 16B granules, 2/thread, coalesced) ----
#pragma unroll
  for (int k = 0; k < 2; ++k) {
    int q = k * 512 + t;
    int arr = q >> 9, rem = q & 511;
    int row = rem >> 4, f8 = rem & 15;
    int grow = row0 + row;
    if (grow > N_NODES - 1) grow = N_NODES - 1;
    const __half* sp = arr ? seg : xh;
    *(float4*)&Ah[arr][row][f8 * 8] = ((const float4*)sp)[(size_t)grow * 16 + f8];
  }
  __syncthreads();

  const int wid = t >> 6, lane = t & 63;
  const int h = wid >> 2, rb = wid & 1, cbg = (wid >> 1) & 1;
  const int c15 = lane & 15, hi = lane >> 4;

  // ---- A fragments: 4 k-chunks of this wave's 16-row block ----
  f16x8 afrag[4];
#pragma unroll
  for (int kc = 0; kc < 4; ++kc)
    afrag[kc] = *(const f16x8*)&Ah[h][rb * 16 + c15][kc * 32 + hi * 8];

  // ---- MFMA: 4 col-tiles x 4 K-chunks ----
  const float4* Wb4 = (const float4*)Wp + h * 2048;   // [c][16 float4 of k-pairs]
  f32x4 acc[4];
#pragma unroll
  for (int ct = 0; ct < 4; ++ct) acc[ct] = (f32x4){0.f, 0.f, 0.f, 0.f};

#pragma unroll
  for (int ct = 0; ct < 4; ++ct) {
    int col_h = cbg * 64 + ct * 16 + c15;
#pragma unroll
    for (int kc = 0; kc < 4; ++kc) {
      float4 br = Wb4[col_h * 16 + kc * 4 + hi];
      acc[ct] = __builtin_amdgcn_mfma_f32_16x16x32_f16(
          afrag[kc], __builtin_bit_cast(f16x8, br), acc[ct], 0, 0, 0);
    }
  }

  // ---- epilogue: +bias, ELU, dropout (bitmask), partial sum-of-squares ----
  float ssr[4] = {0.f, 0.f, 0.f, 0.f};
#pragma unroll
  for (int ct = 0; ct < 4; ++ct) {
    int col_h = cbg * 64 + ct * 16 + c15;
    float b = bias[h * 128 + col_h];
#pragma unroll
    for (int reg = 0; reg < 4; ++reg) {
      unsigned n = row0 + rb * 16 + hi * 4 + reg;
      float val = acc[ct][reg] + b;
      val = (val > 0.0f) ? val : expm1f(val);
      unsigned mw = (n < N_NODES)
                        ? mask[n * 8u + (unsigned)h * 4u + (unsigned)(cbg * 2 + (ct >> 1))]
                        : 0u;
      val = ((mw >> ((ct & 1) * 16 + c15)) & 1u) ? val * (1.0f / 0.7f) : 0.0f;
      acc[ct][reg] = val;
      ssr[reg] = fmaf(val, val, ssr[reg]);
    }
  }
  // reduce over the 16 col-lanes (width 16 stays within the hi group)
#pragma unroll
  for (int d = 1; d < 16; d <<= 1)
#pragma unroll
    for (int reg = 0; reg < 4; ++reg) ssr[reg] += __shfl_xor(ssr[reg], d, 16);
  if (c15 == 0) {
#pragma unroll
    for (int reg = 0; reg < 4; ++reg) wsum[rb][h][cbg][hi * 4 + reg] = ssr[reg];
  }
  __syncthreads();

  // ---- l2norm + store ----
#pragma unroll
  for (int reg = 0; reg < 4; ++reg) {
    int r16 = hi * 4 + reg;
    float tot = wsum[rb][0][0][r16] + wsum[rb][0][1][r16] +
                wsum[rb][1][0][r16] + wsum[rb][1][1][r16];
    float sc = rsqrtf(fmaxf(tot, 1e-12f));
    size_t n = (size_t)(row0 + rb * 16 + r16);
    if (n < N_NODES) {
#pragma unroll
      for (int ct = 0; ct < 4; ++ct)
        out[n * 256 + h * 128 + cbg * 64 + ct * 16 + c15] = acc[ct][reg] * sc;
    }
  }
}

extern "C" void kernel_launch(void* const* d_in, const int* in_sizes, int n_in,
                              void* d_out, int out_size, void* d_ws, size_t ws_size,
                              hipStream_t stream) {
  const float* x      = (const float*)d_in[0];
  const float* Wself  = (const float*)d_in[1];
  const float* Wneigh = (const float*)d_in[2];
  const float* bias   = (const float*)d_in[3];
  const int*   src    = (const int*)d_in[4];   // jnp.int64 degrades to int32 (x64 off)
  const int*   dst    = (const int*)d_in[5];
  float* out = (float*)d_out;

  char* p = (char*)d_ws;
  int*            cursor = (int*)p;                       // 400,000 B (pad 400,896)
  unsigned short* bucket = (unsigned short*)(p + 400896); // 6,400,000 B (slot-major)
  __half*         seg    = (__half*)(p + 6800896);        // 12,800,000 B
  __half*         xh     = (__half*)(p + 19600896);       // 12,800,000 B
  unsigned*       mask   = (unsigned*)(p + 32400896);     // 1,600,000 B
  float*          Wp     = (float*)(p + 34000896);        // 65,536 B (end ~34.1 MB)

  hipMemsetAsync(cursor, 0, 400000, stream);
  prep<<<FILL_BLOCKS + PACK_BLOCKS + WPACK_BLOCKS, 256, 0, stream>>>(
      x, xh, src, dst, Wself, Wneigh, Wp, cursor, bucket, mask);
  gather_kernel<<<N_NODES / 4, 256, 0, stream>>>(xh, cursor, bucket, seg);
  gemm_kernel  <<<NBLK, 512, 0, stream>>>(xh, seg, Wp, bias, mask, out);
}

// Round 24
// 118.951 us; speedup vs baseline: 1.1211x; 1.0733x over previous
//
#include <hip/hip_runtime.h>
#include <hip/hip_fp16.h>
#include <math.h>

#define N_NODES 50000
#define F_DIM   128
#define E_EDGES 800000
#define NPB     32      // nodes per gemm block -> 1563 blocks (last block 16 rows)
#define NBLK    1563
#define SUBCAP  32      // per-parity bucket capacity (Poisson(8): P(>32) ~ 1e-13)
#define APAD_H  136     // padded row stride in halves (272 B = 17 x 16B)
#define NMASKW  400000  // 12.8M elements / 32 bits
#define FILL_BLOCKS 391 // 8 edges/thread: 391*2048 = 800,768 >= E_EDGES
#define PACK_BLOCKS ((N_NODES * F_DIM) / 1024) // 6250
#define WPACK_BLOCKS 64                        // 2*128*64 half2 words / 256

typedef _Float16 f16x8 __attribute__((ext_vector_type(8)));
typedef float    f32x4 __attribute__((ext_vector_type(4)));

// ---------------- JAX threefry (partitionable path, o0^o1) — verified r2 ----------------
__device__ __forceinline__ unsigned rotl32(unsigned x, int d) {
  return (x << d) | (x >> (32 - d));
}

__device__ __forceinline__ void tf2x32(unsigned k0, unsigned k1,
                                       unsigned c0, unsigned c1,
                                       unsigned &o0, unsigned &o1) {
  unsigned ks2 = k0 ^ k1 ^ 0x1BD11BDAu;
  unsigned x0 = c0 + k0, x1 = c1 + k1;
#define TF_R(a) { x0 += x1; x1 = rotl32(x1, a); x1 ^= x0; }
  TF_R(13) TF_R(15) TF_R(26) TF_R(6)   x0 += k1;  x1 += ks2 + 1u;
  TF_R(17) TF_R(29) TF_R(16) TF_R(24)  x0 += ks2; x1 += k0 + 2u;
  TF_R(13) TF_R(15) TF_R(26) TF_R(6)   x0 += k0;  x1 += k1 + 3u;
  TF_R(17) TF_R(29) TF_R(16) TF_R(24)  x0 += k1;  x1 += ks2 + 4u;
  TF_R(13) TF_R(15) TF_R(26) TF_R(6)   x0 += ks2; x1 += k0 + 5u;
#undef TF_R
  o0 = x0; o1 = x1;
}

__device__ __forceinline__ bool keep_elem(unsigned j) {
  unsigned o0, o1;
  tf2x32(0u, 42u, 0u, j, o0, o1);
  unsigned bits = o0 ^ o1;
  float uf = __uint_as_float((bits >> 9) | 0x3f800000u) - 1.0f;
  return uf < 0.7f;
}

// --- prep: fill (8 atomic chains/thread) | fp16 x pack + mask | c-major W pack ---
__global__ __launch_bounds__(256) void prep(const float* __restrict__ x,
                                            __half* __restrict__ xh,
                                            const int* __restrict__ src,
                                            const int* __restrict__ dst,
                                            const float* __restrict__ Wself,
                                            const float* __restrict__ Wneigh,
                                            float* __restrict__ Wp,
                                            int* __restrict__ cursor,
                                            unsigned short* __restrict__ bucket,
                                            unsigned* __restrict__ mask) {
  int b = blockIdx.x;
  if (b < FILL_BLOCKS) {
    // 8 independent {load dst -> atomic -> store} chains per thread
#pragma unroll
    for (int k = 0; k < 8; ++k) {
      int e = b * 2048 + k * 256 + threadIdx.x;
      if (e < E_EDGES) {
        int d = dst[e];
        int par = e & 1;
        int pos = atomicAdd(&cursor[par * N_NODES + d], 1);
        if (pos < SUBCAP)
          bucket[(par * SUBCAP + pos) * N_NODES + d] = (unsigned short)src[e];
      }
    }
  } else if (b < FILL_BLOCKS + PACK_BLOCKS) {
    int i = (b - FILL_BLOCKS) * 256 + threadIdx.x;   // one float4 -> 8B half4
    float4 v = ((const float4*)x)[i];
    __half2 h01 = __floats2half2_rn(v.x, v.y);
    __half2 h23 = __floats2half2_rn(v.z, v.w);
    float2 o;
    o.x = __uint_as_float(*(const unsigned*)&h01);
    o.y = __uint_as_float(*(const unsigned*)&h23);
    ((float2*)xh)[i] = o;
    if (i < NMASKW) {                       // threefry hides under pack's idle VALU
      unsigned base = (unsigned)i * 32u;
      unsigned w = 0;
#pragma unroll 4
      for (int bb = 0; bb < 32; ++bb) w |= (keep_elem(base + bb) ? 1u : 0u) << bb;
      mask[i] = w;
    }
  } else {
    // W pack, c-major k-pairs: Wp[h][c][k2] = half2(W[2k2][c], W[2k2+1][c])
    int idx = (b - FILL_BLOCKS - PACK_BLOCKS) * 256 + threadIdx.x;  // [0, 16384)
    int h = idx >> 13, rem = idx & 8191;
    int k2 = rem >> 7, c = rem & 127;
    const float* Ws = h ? Wneigh : Wself;
    __half2 hh = __floats2half2_rn(Ws[(k2 * 2) * 128 + c], Ws[(k2 * 2 + 1) * 128 + c]);
    Wp[h * 8192 + c * 64 + k2] = __builtin_bit_cast(float, hh);
  }
}

// ---- gather: one 64-lane wave per node; two parity runs; 16 loads in flight ----
__global__ __launch_bounds__(256) void gather_kernel(const __half* __restrict__ xh,
                                                     const int* __restrict__ cursor,
                                                     const unsigned short* __restrict__ bucket,
                                                     __half* __restrict__ seg) {
  const int w = threadIdx.x >> 6, li = threadIdx.x & 63;
  const int n = blockIdx.x * 4 + w;          // 12500 * 4 = 50000 exactly
  int d0 = cursor[n];            d0 = d0 < SUBCAP ? d0 : SUBCAP;
  int d1 = cursor[N_NODES + n];  d1 = d1 < SUBCAP ? d1 : SUBCAP;
  const int deg = d0 + d1;
  __half2 sum = __floats2half2_rn(0.f, 0.f);
  const unsigned* xr = (const unsigned*)xh;  // dword = half2; row stride 64
#pragma unroll
  for (int p = 0; p < 2; ++p) {
    const int dp = p ? d1 : d0;
    const int base = p * SUBCAP;
    for (int j0 = 0; j0 < dp; j0 += 16) {
      int idx[16];
#pragma unroll
      for (int k = 0; k < 16; ++k) {
        int j = j0 + k;
        j = j < dp ? j : dp - 1;             // clamped -> always a valid slot
        idx[k] = bucket[(size_t)(base + j) * N_NODES + n];
      }
      unsigned u[16];
#pragma unroll
      for (int k = 0; k < 16; ++k)
        u[k] = xr[(size_t)idx[k] * 64 + li]; // 16 independent coalesced dwords
#pragma unroll
      for (int k = 0; k < 16; ++k)
        if (j0 + k < dp)
          sum = __hadd2(sum, __builtin_bit_cast(__half2, u[k]));
    }
  }
  float iv = 1.0f / (float)(deg > 1 ? deg : 1);
  float2 f = __half22float2(sum);
  __half2 r = __floats2half2_rn(f.x * iv, f.y * iv);
  ((unsigned*)seg)[(size_t)n * 64 + li] = __builtin_bit_cast(unsigned, r);
}

// ---- gemm: MFMA 16x16x32_f16. 512 thr = 8 waves; wave (h, rb, cbg) owns 4 16x16 tiles ----
// A: row=lane&15, k=(lane>>4)*8+j.  B: col=lane&15, k likewise.
// C/D: col=lane&15, row=(lane>>4)*4+reg  [verified m89 + r18 pass].
__global__ __launch_bounds__(512) void gemm_kernel(
    const __half* __restrict__ xh, const __half* __restrict__ seg,
    const float* __restrict__ Wp, const float* __restrict__ bias,
    const unsigned* __restrict__ mask, float* __restrict__ out) {
  __shared__ __align__(16) __half Ah[2][NPB][APAD_H];   // 17.4 KB
  __shared__ float wsum[2][2][2][16];                   // [rb][h][cbg][row16]

  const int t = threadIdx.x;
  const int row0 = blockIdx.x * NPB;

  // ---- stage self + mean rows (1024 x 16B granules, 2/thread, coalesced) ----
#pragma unroll
  for (int k = 0; k < 2; ++k) {
    int q = k * 512 + t;
    int arr = q >> 9, rem = q & 511;
    int row = rem >> 4, f8 = rem & 15;
    int grow = row0 + row;
    if (grow > N_NODES - 1) grow = N_NODES - 1;
    const __half* sp = arr ? seg : xh;
    *(float4*)&Ah[arr][row][f8 * 8] = ((const float4*)sp)[(size_t)grow * 16 + f8];
  }
  __syncthreads();

  const int wid = t >> 6, lane = t & 63;
  const int h = wid >> 2, rb = wid & 1, cbg = (wid >> 1) & 1;
  const int c15 = lane & 15, hi = lane >> 4;

  // ---- A fragments: 4 k-chunks of this wave's 16-row block ----
  f16x8 afrag[4];
#pragma unroll
  for (int kc = 0; kc < 4; ++kc)
    afrag[kc] = *(const f16x8*)&Ah[h][rb * 16 + c15][kc * 32 + hi * 8];

  // ---- MFMA: 4 col-tiles x 4 K-chunks ----
  const float4* Wb4 = (const float4*)Wp + h * 2048;   // [c][16 float4 of k-pairs]
  f32x4 acc[4];
#pragma unroll
  for (int ct = 0; ct < 4; ++ct) acc[ct] = (f32x4){0.f, 0.f, 0.f, 0.f};

#pragma unroll
  for (int ct = 0; ct < 4; ++ct) {
    int col_h = cbg * 64 + ct * 16 + c15;
#pragma unroll
    for (int kc = 0; kc < 4; ++kc) {
      float4 br = Wb4[col_h * 16 + kc * 4 + hi];
      acc[ct] = __builtin_amdgcn_mfma_f32_16x16x32_f16(
          afrag[kc], __builtin_bit_cast(f16x8, br), acc[ct], 0, 0, 0);
    }
  }

  // ---- epilogue: +bias, ELU, dropout (bitmask), partial sum-of-squares ----
  float ssr[4] = {0.f, 0.f, 0.f, 0.f};
#pragma unroll
  for (int ct = 0; ct < 4; ++ct) {
    int col_h = cbg * 64 + ct * 16 + c15;
    float b = bias[h * 128 + col_h];
#pragma unroll
    for (int reg = 0; reg < 4; ++reg) {
      unsigned n = row0 + rb * 16 + hi * 4 + reg;
      float val = acc[ct][reg] + b;
      val = (val > 0.0f) ? val : expm1f(val);
      unsigned mw = (n < N_NODES)
                        ? mask[n * 8u + (unsigned)h * 4u + (unsigned)(cbg * 2 + (ct >> 1))]
                        : 0u;
      val = ((mw >> ((ct & 1) * 16 + c15)) & 1u) ? val * (1.0f / 0.7f) : 0.0f;
      acc[ct][reg] = val;
      ssr[reg] = fmaf(val, val, ssr[reg]);
    }
  }
  // reduce over the 16 col-lanes (width 16 stays within the hi group)
#pragma unroll
  for (int d = 1; d < 16; d <<= 1)
#pragma unroll
    for (int reg = 0; reg < 4; ++reg) ssr[reg] += __shfl_xor(ssr[reg], d, 16);
  if (c15 == 0) {
#pragma unroll
    for (int reg = 0; reg < 4; ++reg) wsum[rb][h][cbg][hi * 4 + reg] = ssr[reg];
  }
  __syncthreads();

  // ---- l2norm + store ----
#pragma unroll
  for (int reg = 0; reg < 4; ++reg) {
    int r16 = hi * 4 + reg;
    float tot = wsum[rb][0][0][r16] + wsum[rb][0][1][r16] +
                wsum[rb][1][0][r16] + wsum[rb][1][1][r16];
    float sc = rsqrtf(fmaxf(tot, 1e-12f));
    size_t n = (size_t)(row0 + rb * 16 + r16);
    if (n < N_NODES) {
#pragma unroll
      for (int ct = 0; ct < 4; ++ct)
        out[n * 256 + h * 128 + cbg * 64 + ct * 16 + c15] = acc[ct][reg] * sc;
    }
  }
}

extern "C" void kernel_launch(void* const* d_in, const int* in_sizes, int n_in,
                              void* d_out, int out_size, void* d_ws, size_t ws_size,
                              hipStream_t stream) {
  const float* x      = (const float*)d_in[0];
  const float* Wself  = (const float*)d_in[1];
  const float* Wneigh = (const float*)d_in[2];
  const float* bias   = (const float*)d_in[3];
  const int*   src    = (const int*)d_in[4];   // jnp.int64 degrades to int32 (x64 off)
  const int*   dst    = (const int*)d_in[5];
  float* out = (float*)d_out;

  char* p = (char*)d_ws;
  int*            cursor = (int*)p;                       // 400,000 B (pad 400,896)
  unsigned short* bucket = (unsigned short*)(p + 400896); // 6,400,000 B (slot-major)
  __half*         seg    = (__half*)(p + 6800896);        // 12,800,000 B
  __half*         xh     = (__half*)(p + 19600896);       // 12,800,000 B
  unsigned*       mask   = (unsigned*)(p + 32400896);     // 1,600,000 B
  float*          Wp     = (float*)(p + 34000896);        // 65,536 B (end ~34.1 MB)

  hipMemsetAsync(cursor, 0, 400000, stream);
  prep<<<FILL_BLOCKS + PACK_BLOCKS + WPACK_BLOCKS, 256, 0, stream>>>(
      x, xh, src, dst, Wself, Wneigh, Wp, cursor, bucket, mask);
  gather_kernel<<<N_NODES / 4, 256, 0, stream>>>(xh, cursor, bucket, seg);
  gemm_kernel  <<<NBLK, 512, 0, stream>>>(xh, seg, Wp, bias, mask, out);
}

// Round 25
// 117.184 us; speedup vs baseline: 1.1380x; 1.0151x over previous
//
#include <hip/hip_runtime.h>
#include <hip/hip_fp16.h>
#include <math.h>

#define N_NODES 50000
#define F_DIM   128
#define E_EDGES 800000
#define NPB     32      // nodes per gemm block -> 1563 blocks (last block 16 rows)
#define NBLK    1563
#define SUBCAP  32      // per-parity bucket capacity (Poisson(8): P(>32) ~ 1e-13)
#define APAD_H  136     // padded row stride in halves (272 B = 17 x 16B)
#define NMASKW  400000  // 12.8M elements / 32 bits
#define FILL_BLOCKS 196 // 16 edges/thread: 196*4096 = 802,816 >= E_EDGES
#define PACK_BLOCKS ((N_NODES * F_DIM) / 1024) // 6250
#define WPACK_BLOCKS 64                        // 2*128*64 half2 words / 256

typedef _Float16 f16x8 __attribute__((ext_vector_type(8)));
typedef float    f32x4 __attribute__((ext_vector_type(4)));

// ---------------- JAX threefry (partitionable path, o0^o1) — verified r2 ----------------
__device__ __forceinline__ unsigned rotl32(unsigned x, int d) {
  return (x << d) | (x >> (32 - d));
}

__device__ __forceinline__ void tf2x32(unsigned k0, unsigned k1,
                                       unsigned c0, unsigned c1,
                                       unsigned &o0, unsigned &o1) {
  unsigned ks2 = k0 ^ k1 ^ 0x1BD11BDAu;
  unsigned x0 = c0 + k0, x1 = c1 + k1;
#define TF_R(a) { x0 += x1; x1 = rotl32(x1, a); x1 ^= x0; }
  TF_R(13) TF_R(15) TF_R(26) TF_R(6)   x0 += k1;  x1 += ks2 + 1u;
  TF_R(17) TF_R(29) TF_R(16) TF_R(24)  x0 += ks2; x1 += k0 + 2u;
  TF_R(13) TF_R(15) TF_R(26) TF_R(6)   x0 += k0;  x1 += k1 + 3u;
  TF_R(17) TF_R(29) TF_R(16) TF_R(24)  x0 += k1;  x1 += ks2 + 4u;
  TF_R(13) TF_R(15) TF_R(26) TF_R(6)   x0 += ks2; x1 += k0 + 5u;
#undef TF_R
  o0 = x0; o1 = x1;
}

__device__ __forceinline__ bool keep_elem(unsigned j) {
  unsigned o0, o1;
  tf2x32(0u, 42u, 0u, j, o0, o1);
  unsigned bits = o0 ^ o1;
  float uf = __uint_as_float((bits >> 9) | 0x3f800000u) - 1.0f;
  return uf < 0.7f;
}

// --- prep: fill (16 atomic chains/thread) | fp16 x pack + mask | c-major W pack ---
__global__ __launch_bounds__(256) void prep(const float* __restrict__ x,
                                            __half* __restrict__ xh,
                                            const int* __restrict__ src,
                                            const int* __restrict__ dst,
                                            const float* __restrict__ Wself,
                                            const float* __restrict__ Wneigh,
                                            float* __restrict__ Wp,
                                            int* __restrict__ cursor,
                                            unsigned short* __restrict__ bucket,
                                            unsigned* __restrict__ mask) {
  int b = blockIdx.x;
  if (b < FILL_BLOCKS) {
    // 16 independent {load dst -> atomic -> store} chains per thread
#pragma unroll
    for (int k = 0; k < 16; ++k) {
      int e = b * 4096 + k * 256 + threadIdx.x;
      if (e < E_EDGES) {
        int d = dst[e];
        int par = e & 1;
        int pos = atomicAdd(&cursor[par * N_NODES + d], 1);
        if (pos < SUBCAP)
          bucket[(par * SUBCAP + pos) * N_NODES + d] = (unsigned short)src[e];
      }
    }
  } else if (b < FILL_BLOCKS + PACK_BLOCKS) {
    int i = (b - FILL_BLOCKS) * 256 + threadIdx.x;   // one float4 -> 8B half4
    float4 v = ((const float4*)x)[i];
    __half2 h01 = __floats2half2_rn(v.x, v.y);
    __half2 h23 = __floats2half2_rn(v.z, v.w);
    float2 o;
    o.x = __uint_as_float(*(const unsigned*)&h01);
    o.y = __uint_as_float(*(const unsigned*)&h23);
    ((float2*)xh)[i] = o;
    if (i < NMASKW) {                       // threefry hides under pack's idle VALU
      unsigned base = (unsigned)i * 32u;
      unsigned w = 0;
#pragma unroll 4
      for (int bb = 0; bb < 32; ++bb) w |= (keep_elem(base + bb) ? 1u : 0u) << bb;
      mask[i] = w;
    }
  } else {
    // W pack, c-major k-pairs: Wp[h][c][k2] = half2(W[2k2][c], W[2k2+1][c])
    int idx = (b - FILL_BLOCKS - PACK_BLOCKS) * 256 + threadIdx.x;  // [0, 16384)
    int h = idx >> 13, rem = idx & 8191;
    int k2 = rem >> 7, c = rem & 127;
    const float* Ws = h ? Wneigh : Wself;
    __half2 hh = __floats2half2_rn(Ws[(k2 * 2) * 128 + c], Ws[(k2 * 2 + 1) * 128 + c]);
    Wp[h * 8192 + c * 64 + k2] = __builtin_bit_cast(float, hh);
  }
}

// ---- gather: one 64-lane wave per node; two parity runs; 16 loads in flight ----
__global__ __launch_bounds__(256) void gather_kernel(const __half* __restrict__ xh,
                                                     const int* __restrict__ cursor,
                                                     const unsigned short* __restrict__ bucket,
                                                     __half* __restrict__ seg) {
  const int w = threadIdx.x >> 6, li = threadIdx.x & 63;
  const int n = blockIdx.x * 4 + w;          // 12500 * 4 = 50000 exactly
  int d0 = cursor[n];            d0 = d0 < SUBCAP ? d0 : SUBCAP;
  int d1 = cursor[N_NODES + n];  d1 = d1 < SUBCAP ? d1 : SUBCAP;
  const int deg = d0 + d1;
  __half2 sum = __floats2half2_rn(0.f, 0.f);
  const unsigned* xr = (const unsigned*)xh;  // dword = half2; row stride 64
#pragma unroll
  for (int p = 0; p < 2; ++p) {
    const int dp = p ? d1 : d0;
    const int base = p * SUBCAP;
    for (int j0 = 0; j0 < dp; j0 += 16) {
      int idx[16];
#pragma unroll
      for (int k = 0; k < 16; ++k) {
        int j = j0 + k;
        j = j < dp ? j : dp - 1;             // clamped -> always a valid slot
        idx[k] = bucket[(size_t)(base + j) * N_NODES + n];
      }
      unsigned u[16];
#pragma unroll
      for (int k = 0; k < 16; ++k)
        u[k] = xr[(size_t)idx[k] * 64 + li]; // 16 independent coalesced dwords
#pragma unroll
      for (int k = 0; k < 16; ++k)
        if (j0 + k < dp)
          sum = __hadd2(sum, __builtin_bit_cast(__half2, u[k]));
    }
  }
  float iv = 1.0f / (float)(deg > 1 ? deg : 1);
  float2 f = __half22float2(sum);
  __half2 r = __floats2half2_rn(f.x * iv, f.y * iv);
  ((unsigned*)seg)[(size_t)n * 64 + li] = __builtin_bit_cast(unsigned, r);
}

// ---- gemm: MFMA 16x16x32_f16. 512 thr = 8 waves; wave (h, rb, cbg) owns 4 16x16 tiles ----
// A: row=lane&15, k=(lane>>4)*8+j.  B: col=lane&15, k likewise.
// C/D: col=lane&15, row=(lane>>4)*4+reg  [verified m89 + r18 pass].
__global__ __launch_bounds__(512) void gemm_kernel(
    const __half* __restrict__ xh, const __half* __restrict__ seg,
    const float* __restrict__ Wp, const float* __restrict__ bias,
    const unsigned* __restrict__ mask, float* __restrict__ out) {
  __shared__ __align__(16) __half Ah[2][NPB][APAD_H];   // 17.4 KB
  __shared__ float wsum[2][2][2][16];                   // [rb][h][cbg][row16]

  const int t = threadIdx.x;
  const int row0 = blockIdx.x * NPB;

  // ---- stage self + mean rows (1024 x 16B granules, 2/thread, coalesced) ----
#pragma unroll
  for (int k = 0; k < 2; ++k) {
    int q = k * 512 + t;
    int arr = q >> 9, rem = q & 511;
    int row = rem >> 4, f8 = rem & 15;
    int grow = row0 + row;
    if (grow > N_NODES - 1) grow = N_NODES - 1;
    const __half* sp = arr ? seg : xh;
    *(float4*)&Ah[arr][row][f8 * 8] = ((const float4*)sp)[(size_t)grow * 16 + f8];
  }
  __syncthreads();

  const int wid = t >> 6, lane = t & 63;
  const int h = wid >> 2, rb = wid & 1, cbg = (wid >> 1) & 1;
  const int c15 = lane & 15, hi = lane >> 4;

  // ---- A fragments: 4 k-chunks of this wave's 16-row block ----
  f16x8 afrag[4];
#pragma unroll
  for (int kc = 0; kc < 4; ++kc)
    afrag[kc] = *(const f16x8*)&Ah[h][rb * 16 + c15][kc * 32 + hi * 8];

  // ---- MFMA: 4 col-tiles x 4 K-chunks ----
  const float4* Wb4 = (const float4*)Wp + h * 2048;   // [c][16 float4 of k-pairs]
  f32x4 acc[4];
#pragma unroll
  for (int ct = 0; ct < 4; ++ct) acc[ct] = (f32x4){0.f, 0.f, 0.f, 0.f};

#pragma unroll
  for (int ct = 0; ct < 4; ++ct) {
    int col_h = cbg * 64 + ct * 16 + c15;
#pragma unroll
    for (int kc = 0; kc < 4; ++kc) {
      float4 br = Wb4[col_h * 16 + kc * 4 + hi];
      acc[ct] = __builtin_amdgcn_mfma_f32_16x16x32_f16(
          afrag[kc], __builtin_bit_cast(f16x8, br), acc[ct], 0, 0, 0);
    }
  }

  // ---- epilogue: +bias, ELU, dropout (bitmask), partial sum-of-squares ----
  float ssr[4] = {0.f, 0.f, 0.f, 0.f};
#pragma unroll
  for (int ct = 0; ct < 4; ++ct) {
    int col_h = cbg * 64 + ct * 16 + c15;
    float b = bias[h * 128 + col_h];
#pragma unroll
    for (int reg = 0; reg < 4; ++reg) {
      unsigned n = row0 + rb * 16 + hi * 4 + reg;
      float val = acc[ct][reg] + b;
      val = (val > 0.0f) ? val : expm1f(val);
      unsigned mw = (n < N_NODES)
                        ? mask[n * 8u + (unsigned)h * 4u + (unsigned)(cbg * 2 + (ct >> 1))]
                        : 0u;
      val = ((mw >> ((ct & 1) * 16 + c15)) & 1u) ? val * (1.0f / 0.7f) : 0.0f;
      acc[ct][reg] = val;
      ssr[reg] = fmaf(val, val, ssr[reg]);
    }
  }
  // reduce over the 16 col-lanes (width 16 stays within the hi group)
#pragma unroll
  for (int d = 1; d < 16; d <<= 1)
#pragma unroll
    for (int reg = 0; reg < 4; ++reg) ssr[reg] += __shfl_xor(ssr[reg], d, 16);
  if (c15 == 0) {
#pragma unroll
    for (int reg = 0; reg < 4; ++reg) wsum[rb][h][cbg][hi * 4 + reg] = ssr[reg];
  }
  __syncthreads();

  // ---- l2norm + store ----
#pragma unroll
  for (int reg = 0; reg < 4; ++reg) {
    int r16 = hi * 4 + reg;
    float tot = wsum[rb][0][0][r16] + wsum[rb][0][1][r16] +
                wsum[rb][1][0][r16] + wsum[rb][1][1][r16];
    float sc = rsqrtf(fmaxf(tot, 1e-12f));
    size_t n = (size_t)(row0 + rb * 16 + r16);
    if (n < N_NODES) {
#pragma unroll
      for (int ct = 0; ct < 4; ++ct)
        out[n * 256 + h * 128 + cbg * 64 + ct * 16 + c15] = acc[ct][reg] * sc;
    }
  }
}

extern "C" void kernel_launch(void* const* d_in, const int* in_sizes, int n_in,
                              void* d_out, int out_size, void* d_ws, size_t ws_size,
                              hipStream_t stream) {
  const float* x      = (const float*)d_in[0];
  const float* Wself  = (const float*)d_in[1];
  const float* Wneigh = (const float*)d_in[2];
  const float* bias   = (const float*)d_in[3];
  const int*   src    = (const int*)d_in[4];   // jnp.int64 degrades to int32 (x64 off)
  const int*   dst    = (const int*)d_in[5];
  float* out = (float*)d_out;

  char* p = (char*)d_ws;
  int*            cursor = (int*)p;                       // 400,000 B (pad 400,896)
  unsigned short* bucket = (unsigned short*)(p + 400896); // 6,400,000 B (slot-major)
  __half*         seg    = (__half*)(p + 6800896);        // 12,800,000 B
  __half*         xh     = (__half*)(p + 19600896);       // 12,800,000 B
  unsigned*       mask   = (unsigned*)(p + 32400896);     // 1,600,000 B
  float*          Wp     = (float*)(p + 34000896);        // 65,536 B (end ~34.1 MB)

  hipMemsetAsync(cursor, 0, 400000, stream);
  prep<<<FILL_BLOCKS + PACK_BLOCKS + WPACK_BLOCKS, 256, 0, stream>>>(
      x, xh, src, dst, Wself, Wneigh, Wp, cursor, bucket, mask);
  gather_kernel<<<N_NODES / 4, 256, 0, stream>>>(xh, cursor, bucket, seg);
  gemm_kernel  <<<NBLK, 512, 0, stream>>>(xh, seg, Wp, bias, mask, out);
}